// Round 2
// baseline (7017.907 us; speedup 1.0000x reference)
//
#include <hip/hip_runtime.h>
#include <hip/hip_bf16.h>
#include <math.h>

#define B_ 16
#define L_ 100
#define D_ 512
#define HW_ 16384
#define H_ 8

using bf16x8 = __attribute__((ext_vector_type(8))) short;
using f32x4  = __attribute__((ext_vector_type(4))) float;

__device__ __forceinline__ unsigned short f2bf(float x) {
    unsigned u = __float_as_uint(x);
    u += 0x7fffu + ((u >> 16) & 1u);
    return (unsigned short)(u >> 16);
}
__device__ __forceinline__ float bf2f(unsigned short b) {
    return __uint_as_float(((unsigned)b) << 16);
}
// pack {lo.hi16, hi.hi16} -> one dword (two bf16 via truncation)
__device__ __forceinline__ unsigned prm(unsigned hi, unsigned lo) {
#if defined(__has_builtin)
#if __has_builtin(__builtin_amdgcn_perm)
    return __builtin_amdgcn_perm(hi, lo, 0x07060302u);
#else
    return (lo >> 16) | (hi & 0xFFFF0000u);
#endif
#else
    return (lo >> 16) | (hi & 0xFFFF0000u);
#endif
}

// ---------------------------------------------------------------------------
// Generic tiled GEMM:  C = alpha*(A @ B^T) [+ bias] [+ residual] [relu]
// (unchanged)
// ---------------------------------------------------------------------------
__global__ __launch_bounds__(256) void gemm_bt(
    const float* __restrict__ A, const float* __restrict__ Bm,
    const float* __restrict__ Cres, const float* __restrict__ bias,
    float* __restrict__ C,
    int M, int N, int K, int lda, int ldb, int ldc,
    int zmod, long sA, long sB, long sC1, long sC2,
    float alpha, int relu)
{
    const int z = blockIdx.z;
    const long aOff = (long)z * sA;
    const long bOff = (long)(z % zmod) * sB;
    const long cOff = (long)(z / zmod) * sC1 + (long)(z % zmod) * sC2;

    __shared__ float As[16][65];
    __shared__ float Bs[16][65];

    const int tid = threadIdx.x;
    const int tx = tid & 15, ty = tid >> 4;
    const int m0 = blockIdx.y * 64, n0 = blockIdx.x * 64;
    const int lr = tid & 63;
    const int lk = (tid >> 6) * 4;

    float acc[4][4];
#pragma unroll
    for (int i = 0; i < 4; ++i)
#pragma unroll
        for (int j = 0; j < 4; ++j) acc[i][j] = 0.f;

    for (int k0 = 0; k0 < K; k0 += 16) {
        __syncthreads();
        {
            float4 v = make_float4(0.f, 0.f, 0.f, 0.f);
            const int gr = m0 + lr;
            if (gr < M) v = *(const float4*)&A[aOff + (long)gr * lda + k0 + lk];
            As[lk + 0][lr] = v.x; As[lk + 1][lr] = v.y;
            As[lk + 2][lr] = v.z; As[lk + 3][lr] = v.w;
            const float4 w = *(const float4*)&Bm[bOff + (long)(n0 + lr) * ldb + k0 + lk];
            Bs[lk + 0][lr] = w.x; Bs[lk + 1][lr] = w.y;
            Bs[lk + 2][lr] = w.z; Bs[lk + 3][lr] = w.w;
        }
        __syncthreads();
#pragma unroll
        for (int k = 0; k < 16; ++k) {
            float a[4], bb[4];
#pragma unroll
            for (int i = 0; i < 4; ++i) a[i] = As[k][ty + 16 * i];
#pragma unroll
            for (int j = 0; j < 4; ++j) bb[j] = Bs[k][tx + 16 * j];
#pragma unroll
            for (int i = 0; i < 4; ++i)
#pragma unroll
                for (int j = 0; j < 4; ++j) acc[i][j] += a[i] * bb[j];
        }
    }

#pragma unroll
    for (int i = 0; i < 4; ++i) {
        const int r = m0 + ty + 16 * i;
        if (r >= M) continue;
#pragma unroll
        for (int j = 0; j < 4; ++j) {
            const int c = n0 + tx + 16 * j;
            float vv = alpha * acc[i][j];
            if (bias) vv += bias[c];
            if (Cres) vv += Cres[cOff + (long)r * ldc + c];
            if (relu) vv = fmaxf(vv, 0.f);
            C[cOff + (long)r * ldc + c] = vv;
        }
    }
}

// ---------------------------------------------------------------------------
// qW[b,h,l,c] = sum_d q[b,l,h*64+d] * Wk[h*64+d, c]
// Now emits the bf16 hi/lo split (round-to-nearest) directly.
// ---------------------------------------------------------------------------
__global__ __launch_bounds__(256) void qw_kernel(
    const float* __restrict__ q, const float* __restrict__ Wk,
    unsigned short* __restrict__ qwh, unsigned short* __restrict__ qwl)
{
    const int bz = blockIdx.x;
    const int b = bz >> 3, h = bz & 7;
    __shared__ float q_s[L_][64];

    const int tid = threadIdx.x;
#pragma unroll
    for (int t = 0; t < 25; ++t) {
        const int idx = tid + 256 * t;
        const int l = idx >> 6, d = idx & 63;
        q_s[l][d] = q[((long)(b * L_ + l)) * D_ + h * 64 + d];
    }
    __syncthreads();

    const float* Wh = Wk + (long)h * 64 * D_;
    for (int lb = 0; lb < 10; ++lb) {
        float acc0[10], acc1[10];
#pragma unroll
        for (int ll = 0; ll < 10; ++ll) { acc0[ll] = 0.f; acc1[ll] = 0.f; }
        for (int d = 0; d < 64; ++d) {
            const float w0 = Wh[(long)d * D_ + tid];
            const float w1 = Wh[(long)d * D_ + tid + 256];
#pragma unroll
            for (int ll = 0; ll < 10; ++ll) {
                const float qv = q_s[lb * 10 + ll][d];
                acc0[ll] += qv * w0;
                acc1[ll] += qv * w1;
            }
        }
#pragma unroll
        for (int ll = 0; ll < 10; ++ll) {
            const long o = (((long)(b * H_ + h)) * L_ + lb * 10 + ll) * D_;
            const unsigned short h0 = f2bf(acc0[ll]);
            const unsigned short h1 = f2bf(acc1[ll]);
            qwh[o + tid]       = h0;
            qwh[o + tid + 256] = h1;
            qwl[o + tid]       = f2bf(acc0[ll] - bf2f(h0));
            qwl[o + tid + 256] = f2bf(acc1[ll] - bf2f(h1));
        }
    }
}

// ---------------------------------------------------------------------------
// MFMA flash attention v2.
//  - qw A-fragments streamed from pre-split global bf16 (L2-hot), no q regs/LDS.
//  - Truncation hi/lo split for feats (lo absorbs the error exactly).
//  - All LDS tiles XOR-swizzled (16B granule ^ row&7) -> <=2-way banks.
//  - T14: global loads for dc+1 issued before MFMA of dc; pass-B dc0 loads
//    issued before dump (hidden under mask/softmax).
//  - LDS 49.4KB (32KB shared A/B tile region + 16KB ssf with P overlaid
//    in-place per row) -> 3 blocks/CU at VGPR<=168.
//  - XCD-grouped block mapping: each XCD's L2 serves 2 batches' feats.
// ---------------------------------------------------------------------------
__global__ __launch_bounds__(256, 3) void flash_attn(
    const unsigned short* __restrict__ qwh,
    const unsigned short* __restrict__ qwl,
    const float* __restrict__ feats,
    float* __restrict__ ctx, float* __restrict__ mask_out)
{
    // LDS:
    //  R0 [0,32768):  pass A fh[128][64]bf16 | fl (+16384)   (swz: g=d>>3 ^ m&7)
    //                 pass B fth[64][128]bf16 | ftl (+16384)  (swz: g=m>>3 ^ d&7)
    //  R1 [32768,49152): 32 rows x 512B: ssf f32[128] (swz g=c>>2 ^ r&7)
    //                    overlaid after softmax: P-hi [0,256) | P-lo [256,512)
    //  alpha_s @49152, sum_s @49280
    __shared__ __align__(16) char smem[49408];
    char* const R0 = smem;
    char* const R1 = smem + 32768;
    float* const alpha_s = (float*)(smem + 49152);
    float* const sum_s   = (float*)(smem + 49280);

    const int tid  = threadIdx.x;
    const int lane = tid & 63;
    const int w    = tid >> 6;
    const int mw   = w >> 1, nw = w & 1;
    const int ln15 = lane & 15;
    const int lg   = lane >> 4;
    const int kl8  = lg * 8, kl4 = lg * 4;

    // XCD-grouped mapping: hw block i -> xcd i&7; 50 slots = 2 batches x 25 lgroups
    const int hwb  = blockIdx.x;
    const int slot = hwb >> 3;
    const int b    = (hwb & 7) * 2 + (slot >= 25 ? 1 : 0);
    const int l0   = (slot >= 25 ? slot - 25 : slot) * 4;

    const long fbase = (long)b * HW_ * D_;

    const int hl_a = mw * 16 + ln15;
    const long qoff = (((long)(b * H_ + (hl_a >> 2))) * L_ + (l0 + (hl_a & 3))) * D_;

    // dc-invariant swizzled LDS byte offsets
    int offA[2][4];
#pragma unroll
    for (int t = 0; t < 4; ++t) {
        const int r = (nw + 2 * t) * 16 + ln15;
#pragma unroll
        for (int kt = 0; kt < 2; ++kt)
            offA[kt][t] = r * 128 + (((kt * 4 + lg) ^ (r & 7)) << 4);
    }
    int offB[4][2];
#pragma unroll
    for (int t = 0; t < 2; ++t) {
        const int r = (nw + 2 * t) * 16 + ln15;
#pragma unroll
        for (int kt = 0; kt < 4; ++kt)
            offB[kt][t] = r * 256 + (((kt * 4 + lg) ^ (r & 7)) << 4);
    }
    int offP[4];
    {
        const int r = mw * 16 + ln15;
#pragma unroll
        for (int kt = 0; kt < 4; ++kt)
            offP[kt] = r * 512 + (((kt * 4 + lg) ^ (r & 7)) << 4);
    }

    const int srow = tid >> 3, slan = tid & 7;
    const int mp = tid & 63;          // pass-B m-pair index (d-quarter = wave id)

    float run_max = -INFINITY, run_sum = 0.f;
    f32x4 cacc[8][2];
#pragma unroll
    for (int i = 0; i < 8; ++i)
#pragma unroll
        for (int j = 0; j < 2; ++j) cacc[i][j] = (f32x4){0.f, 0.f, 0.f, 0.f};

    for (int m0 = 0; m0 < HW_; m0 += 128) {
        // ================= pass A: S = qw @ feats^T =================
        f32x4 sacc[4];
#pragma unroll
        for (int t = 0; t < 4; ++t) sacc[t] = (f32x4){0.f, 0.f, 0.f, 0.f};

        float4 vA[8];
        bf16x8 nqh0, nqh1, nql0, nql1;
        {   // prefetch dc=0
            const float* fp = feats + fbase + (long)m0 * D_;
#pragma unroll
            for (int it = 0; it < 8; ++it) {
                const int f4 = tid + 256 * it;
                vA[it] = *(const float4*)&fp[(long)(f4 >> 4) * D_ + (f4 & 15) * 4];
            }
            nqh0 = *(const bf16x8*)(qwh + qoff + kl8);
            nqh1 = *(const bf16x8*)(qwh + qoff + 32 + kl8);
            nql0 = *(const bf16x8*)(qwl + qoff + kl8);
            nql1 = *(const bf16x8*)(qwl + qoff + 32 + kl8);
        }

#pragma unroll
        for (int dc = 0; dc < 8; ++dc) {
            const bf16x8 qh0 = nqh0, qh1 = nqh1, ql0 = nql0, ql1 = nql1;
            __syncthreads();                       // prior readers of R0 done
            // convert + swizzled store (trunc split; lo is exact remainder)
#pragma unroll
            for (int it = 0; it < 8; ++it) {
                const int f4 = tid + 256 * it;
                const int r = f4 >> 4, c4 = f4 & 15;
                const float4 vv = vA[it];
                const unsigned u0 = __float_as_uint(vv.x), u1 = __float_as_uint(vv.y);
                const unsigned u2 = __float_as_uint(vv.z), u3 = __float_as_uint(vv.w);
                const float e0 = vv.x - __uint_as_float(u0 & 0xFFFF0000u);
                const float e1 = vv.y - __uint_as_float(u1 & 0xFFFF0000u);
                const float e2 = vv.z - __uint_as_float(u2 & 0xFFFF0000u);
                const float e3 = vv.w - __uint_as_float(u3 & 0xFFFF0000u);
                const int off = r * 128 + ((((c4 >> 1) ^ (r & 7)) << 4)) + ((c4 & 1) << 3);
                *(uint2*)(R0 + off) = make_uint2(prm(u1, u0), prm(u3, u2));
                *(uint2*)(R0 + 16384 + off) =
                    make_uint2(prm(__float_as_uint(e1), __float_as_uint(e0)),
                               prm(__float_as_uint(e3), __float_as_uint(e2)));
            }
            __syncthreads();
            if (dc < 7) {                          // prefetch dc+1 (hides under MFMA)
                const float* fp = feats + fbase + (long)m0 * D_ + (dc + 1) * 64;
#pragma unroll
                for (int it = 0; it < 8; ++it) {
                    const int f4 = tid + 256 * it;
                    vA[it] = *(const float4*)&fp[(long)(f4 >> 4) * D_ + (f4 & 15) * 4];
                }
                const long qo = qoff + (dc + 1) * 64 + kl8;
                nqh0 = *(const bf16x8*)(qwh + qo);
                nqh1 = *(const bf16x8*)(qwh + qo + 32);
                nql0 = *(const bf16x8*)(qwl + qo);
                nql1 = *(const bf16x8*)(qwl + qo + 32);
            }
#pragma unroll
            for (int kt = 0; kt < 2; ++kt) {
                const bf16x8 qh = kt ? qh1 : qh0;
                const bf16x8 ql = kt ? ql1 : ql0;
#pragma unroll
                for (int t = 0; t < 4; ++t) {
                    const char* bp = R0 + offA[kt][t];
                    const bf16x8 bh = *(const bf16x8*)bp;
                    const bf16x8 bl = *(const bf16x8*)(bp + 16384);
                    sacc[t] = __builtin_amdgcn_mfma_f32_16x16x32_bf16(qh, bh, sacc[t], 0, 0, 0);
                    sacc[t] = __builtin_amdgcn_mfma_f32_16x16x32_bf16(qh, bl, sacc[t], 0, 0, 0);
                    sacc[t] = __builtin_amdgcn_mfma_f32_16x16x32_bf16(ql, bh, sacc[t], 0, 0, 0);
                }
            }
        }

        // issue pass-B dc=0 loads now: latency hides under dump/mask/softmax
        float4 vB[8];
        {
            const float* fp = feats + fbase + (long)m0 * D_ + w * 16;
#pragma unroll
            for (int i = 0; i < 4; ++i) {
                vB[2 * i]     = *(const float4*)&fp[(long)(2 * mp) * D_ + 4 * i];
                vB[2 * i + 1] = *(const float4*)&fp[(long)(2 * mp + 1) * D_ + 4 * i];
            }
        }

        // ---- dump raw scores to ssf (R1 untouched since prev chunk's P reads) ----
#pragma unroll
        for (int t = 0; t < 4; ++t) {
            const int col = (nw + 2 * t) * 16 + ln15;
#pragma unroll
            for (int r = 0; r < 4; ++r) {
                const int row = mw * 16 + kl4 + r;
                *(float*)(R1 + row * 512 + ((((col >> 2) ^ (row & 7)) << 4)) + ((col & 3) << 2)) = sacc[t][r];
            }
        }
        __syncthreads();

        // ---- mask: head-sum of raw scores ----
        {
            const int li = tid >> 6, mm = tid & 63;
#pragma unroll
            for (int rep = 0; rep < 2; ++rep) {
                const int m = mm + 64 * rep;
                float s = 0.f;
#pragma unroll
                for (int hh = 0; hh < 8; ++hh) {
                    const int row = hh * 4 + li;
                    s += *(const float*)(R1 + row * 512 + ((((m >> 2) ^ (row & 7)) << 4)) + ((m & 3) << 2));
                }
                mask_out[((long)(b * L_ + l0 + li)) * HW_ + m0 + m] = s;
            }
        }
        // softmax row reads (must complete before P overwrites ssf)
        float v[16];
#pragma unroll
        for (int q4 = 0; q4 < 4; ++q4) {
            const float4 t4 = *(const float4*)(R1 + srow * 512 + ((((slan * 4 + q4) ^ (srow & 7)) << 4)));
            v[q4 * 4 + 0] = t4.x; v[q4 * 4 + 1] = t4.y;
            v[q4 * 4 + 2] = t4.z; v[q4 * 4 + 3] = t4.w;
        }
        __syncthreads();   // all ssf reads done -> P may overwrite

        // ---- online softmax; P -> bf16 hi/lo overlaid on own ssf row ----
        {
            float mx = v[0];
#pragma unroll
            for (int k = 1; k < 16; ++k) mx = fmaxf(mx, v[k]);
#pragma unroll
            for (int o = 4; o > 0; o >>= 1) mx = fmaxf(mx, __shfl_xor(mx, o, 8));
            const float nm = fmaxf(run_max, mx);
            const float al = __expf(run_max - nm);
            float cs = 0.f;
            unsigned hp[8], lp[8];
#pragma unroll
            for (int j = 0; j < 8; ++j) {
                const float p0 = __expf(v[2 * j] - nm);
                const float p1 = __expf(v[2 * j + 1] - nm);
                cs += p0 + p1;
                const unsigned a = __float_as_uint(p0), bu = __float_as_uint(p1);
                hp[j] = prm(bu, a);
                const float q0 = p0 - __uint_as_float(a & 0xFFFF0000u);
                const float q1 = p1 - __uint_as_float(bu & 0xFFFF0000u);
                lp[j] = prm(__float_as_uint(q1), __float_as_uint(q0));
            }
            char* prow = R1 + srow * 512;
            const int g0 = ((slan * 2) ^ (srow & 7)) << 4;
            const int g1 = ((slan * 2 + 1) ^ (srow & 7)) << 4;
            *(uint4*)(prow + g0) = make_uint4(hp[0], hp[1], hp[2], hp[3]);
            *(uint4*)(prow + g1) = make_uint4(hp[4], hp[5], hp[6], hp[7]);
            *(uint4*)(prow + 256 + g0) = make_uint4(lp[0], lp[1], lp[2], lp[3]);
            *(uint4*)(prow + 256 + g1) = make_uint4(lp[4], lp[5], lp[6], lp[7]);
#pragma unroll
            for (int o = 4; o > 0; o >>= 1) cs += __shfl_xor(cs, o, 8);
            run_sum = run_sum * al + cs;
            run_max = nm;
            if (slan == 0) alpha_s[srow] = al;
        }
        __syncthreads();

        // rescale accumulators
        {
            float alr[4];
#pragma unroll
            for (int r = 0; r < 4; ++r) alr[r] = alpha_s[mw * 16 + kl4 + r];
#pragma unroll
            for (int i = 0; i < 8; ++i)
#pragma unroll
                for (int j = 0; j < 2; ++j)
#pragma unroll
                    for (int r = 0; r < 4; ++r) cacc[i][j][r] *= alr[r];
        }

        // ================= pass B: ctx += P @ feats =================
#pragma unroll
        for (int dc = 0; dc < 8; ++dc) {
            __syncthreads();                       // prior readers of R0 done
            // transposed convert + swizzled store: ft[d][m] (wave w owns d-quarter)
#pragma unroll
            for (int i = 0; i < 4; ++i) {
                const float4 va = vB[2 * i], vb = vB[2 * i + 1];
                const float af[4] = {va.x, va.y, va.z, va.w};
                const float bf[4] = {vb.x, vb.y, vb.z, vb.w};
#pragma unroll
                for (int j = 0; j < 4; ++j) {
                    const int d = w * 16 + 4 * i + j;
                    const unsigned ua = __float_as_uint(af[j]);
                    const unsigned ub = __float_as_uint(bf[j]);
                    const float ea = af[j] - __uint_as_float(ua & 0xFFFF0000u);
                    const float eb = bf[j] - __uint_as_float(ub & 0xFFFF0000u);
                    const int off = d * 256 + ((((mp >> 2) ^ (d & 7)) << 4)) + ((mp & 3) << 2);
                    *(unsigned*)(R0 + off) = prm(ub, ua);
                    *(unsigned*)(R0 + 16384 + off) = prm(__float_as_uint(eb), __float_as_uint(ea));
                }
            }
            __syncthreads();
            if (dc < 7) {                          // prefetch dc+1
                const float* fp = feats + fbase + (long)m0 * D_ + (dc + 1) * 64 + w * 16;
#pragma unroll
                for (int i = 0; i < 4; ++i) {
                    vB[2 * i]     = *(const float4*)&fp[(long)(2 * mp) * D_ + 4 * i];
                    vB[2 * i + 1] = *(const float4*)&fp[(long)(2 * mp + 1) * D_ + 4 * i];
                }
            }
#pragma unroll
            for (int kt = 0; kt < 4; ++kt) {
                const bf16x8 ph = *(const bf16x8*)(R1 + offP[kt]);
                const bf16x8 pl = *(const bf16x8*)(R1 + offP[kt] + 256);
#pragma unroll
                for (int t = 0; t < 2; ++t) {
                    const char* bp = R0 + offB[kt][t];
                    const bf16x8 bh = *(const bf16x8*)bp;
                    const bf16x8 bl = *(const bf16x8*)(bp + 16384);
                    cacc[dc][t] = __builtin_amdgcn_mfma_f32_16x16x32_bf16(ph, bh, cacc[dc][t], 0, 0, 0);
                    cacc[dc][t] = __builtin_amdgcn_mfma_f32_16x16x32_bf16(ph, bl, cacc[dc][t], 0, 0, 0);
                    cacc[dc][t] = __builtin_amdgcn_mfma_f32_16x16x32_bf16(pl, bh, cacc[dc][t], 0, 0, 0);
                }
            }
        }
    }

    // ---- writeout: normalize by softmax denominator ----
    if (slan == 0) sum_s[srow] = run_sum;
    __syncthreads();
#pragma unroll
    for (int r = 0; r < 4; ++r) {
        const int hl = mw * 16 + kl4 + r;
        const float inv = 1.f / sum_s[hl];
        const long base = (((long)(b * H_ + (hl >> 2))) * L_ + (l0 + (hl & 3))) * D_;
#pragma unroll
        for (int dc = 0; dc < 8; ++dc)
#pragma unroll
            for (int t = 0; t < 2; ++t)
                ctx[base + dc * 64 + (nw + 2 * t) * 16 + ln15] = cacc[dc][t][r] * inv;
    }
}

// ---------------------------------------------------------------------------
// Row LayerNorm over 512 cols. One block per row. (unchanged)
// ---------------------------------------------------------------------------
__global__ __launch_bounds__(256) void ln_kernel(
    const float* __restrict__ X, const float* __restrict__ w,
    const float* __restrict__ bb, float* __restrict__ out)
{
    const int row = blockIdx.x;
    const int tid = threadIdx.x;
    const long base = (long)row * D_;
    const float x0 = X[base + tid];
    const float x1 = X[base + tid + 256];
    float s = x0 + x1;
    float sq = x0 * x0 + x1 * x1;
#pragma unroll
    for (int o = 32; o > 0; o >>= 1) {
        s  += __shfl_xor(s, o, 64);
        sq += __shfl_xor(sq, o, 64);
    }
    __shared__ float ws_[4], wq_[4];
    const int wid = tid >> 6, lane = tid & 63;
    if (lane == 0) { ws_[wid] = s; wq_[wid] = sq; }
    __syncthreads();
    s  = ws_[0] + ws_[1] + ws_[2] + ws_[3];
    sq = wq_[0] + wq_[1] + wq_[2] + wq_[3];
    const float mu = s * (1.f / 512.f);
    const float var = sq * (1.f / 512.f) - mu * mu;
    const float rs = rsqrtf(var + 1e-5f);
    out[base + tid]       = (x0 - mu) * rs * w[tid] + bb[tid];
    out[base + tid + 256] = (x1 - mu) * rs * w[tid + 256] + bb[tid + 256];
}

// ---------------------------------------------------------------------------
extern "C" void kernel_launch(void* const* d_in, const int* in_sizes, int n_in,
                              void* d_out, int out_size, void* d_ws, size_t ws_size,
                              hipStream_t stream)
{
    const float* query = (const float*)d_in[0];
    const float* feats = (const float*)d_in[1];
    const float* Wq    = (const float*)d_in[2];
    const float* Wk    = (const float*)d_in[3];
    const float* Wv    = (const float*)d_in[4];
    const float* Wp    = (const float*)d_in[5];
    const float* bp    = (const float*)d_in[6];
    const float* W1    = (const float*)d_in[7];
    const float* b1    = (const float*)d_in[8];
    const float* W2    = (const float*)d_in[9];
    const float* b2    = (const float*)d_in[10];
    const float* ln0w  = (const float*)d_in[11];
    const float* ln0b  = (const float*)d_in[12];
    const float* ln2w  = (const float*)d_in[13];
    const float* ln2b  = (const float*)d_in[14];

    float* out = (float*)d_out;            // [y: 819200][mask: 26214400]
    float* ws  = (float*)d_ws;

    // ws layout (float offsets / byte spans):
    //   q    : [0, 819200)                       3.28 MB
    //   qwh  : floats [819200, 4096000)   = 6.55M ushort (13.1 MB)
    //   qwl  : floats [4096000, 7372800)  = 6.55M ushort (13.1 MB)
    //   ctx  : [7372800, 13926400)               26.2 MB
    //   attno: reuse q region (dead after qw_kernel)
    //   xin/x/h1/ffnp: reuse qwh/qwl span (dead after flash)
    float* q = ws;
    unsigned short* qwh = (unsigned short*)(ws + 819200);
    unsigned short* qwl = (unsigned short*)(ws + 4096000);
    float* ctx   = ws + 7372800;
    float* attno = ws;
    float* xin   = ws + 819200;
    float* x     = ws + 1638400;
    float* h1    = ws + 2457600;
    float* ffnp  = ws + 3276800;

    const dim3 thr(256);

    // q = 0.125 * query @ Wq.T        [1600 x 512, K=512]
    gemm_bt<<<dim3(8, 25, 1), thr, 0, stream>>>(
        query, Wq, nullptr, nullptr, q,
        1600, 512, 512, 512, 512, 512, 1, 0, 0, 0, 0, 0.125f, 0);

    // qW[b,h,l,:] = q_head @ Wk_head  -> bf16 hi/lo split
    qw_kernel<<<dim3(128), thr, 0, stream>>>(q, Wk, qwh, qwl);

    // fused scores + mask + online softmax + ctx accumulation (MFMA)
    flash_attn<<<dim3(400), thr, 0, stream>>>(qwh, qwl, feats, ctx, out + 819200);

    // attno[b,l,h*64+d] = ctx[b,h,l,:] . Wv[h*64+d,:]  (batched over 128 (b,h))
    gemm_bt<<<dim3(1, 2, 128), thr, 0, stream>>>(
        ctx, Wv, nullptr, nullptr, attno,
        100, 64, 512, 512, 512, 512, 8, 51200, 32768, 51200, 64, 1.f, 0);

    // xin = query + attno @ Wp.T + bp
    gemm_bt<<<dim3(8, 25, 1), thr, 0, stream>>>(
        attno, Wp, query, bp, xin,
        1600, 512, 512, 512, 512, 512, 1, 0, 0, 0, 0, 1.f, 0);

    // x = LN0(xin)
    ln_kernel<<<dim3(1600), thr, 0, stream>>>(xin, ln0w, ln0b, x);

    // h1 = relu(x @ W1.T + b1)
    gemm_bt<<<dim3(8, 25, 1), thr, 0, stream>>>(
        x, W1, nullptr, b1, h1,
        1600, 512, 512, 512, 512, 512, 1, 0, 0, 0, 0, 1.f, 1);

    // ffnp = x + h1 @ W2.T + b2
    gemm_bt<<<dim3(8, 25, 1), thr, 0, stream>>>(
        h1, W2, x, b2, ffnp,
        1600, 512, 512, 512, 512, 512, 1, 0, 0, 0, 0, 1.f, 0);

    // y = LN2(ffnp) -> d_out
    ln_kernel<<<dim3(1600), thr, 0, stream>>>(ffnp, ln2w, ln2b, out);
}